// Round 2
// baseline (449.104 us; speedup 1.0000x reference)
//
#include <hip/hip_runtime.h>

typedef unsigned short u16;
typedef __attribute__((ext_vector_type(8))) short bf16x8;
typedef __attribute__((ext_vector_type(4))) float f32x4;

struct __align__(8) u16x4_t { u16 x, y, z, w; };

__device__ __forceinline__ float b2f(u16 b) {
  union { unsigned u; float f; } v; v.u = ((unsigned)b) << 16; return v.f;
}
__device__ __forceinline__ u16 f2b(float f) {
  union { float f; unsigned u; } v; v.f = f;
  unsigned r = v.u + 0x7fffu + ((v.u >> 16) & 1u);
  return (u16)(r >> 16);
}

// ---------------- prep: evtX cvt + weight cvt + mask/mlist build, one dispatch ----------------
__global__ void prep(const float* __restrict__ evtX, u16* __restrict__ evtb, int nEvtF4,
                     const float* __restrict__ Wp, const float* __restrict__ Wi,
                     const float* __restrict__ Wh, u16* __restrict__ wb,
                     const int* __restrict__ main_idx, int* __restrict__ mask,
                     int* __restrict__ mlist, int* __restrict__ cpos,
                     int* __restrict__ mcount, int nMain) {
  const int cvtBlocks = nEvtF4 / 256;           // 25000
  int b = blockIdx.x;
  if (b < cvtBlocks) {
    int t = b * 256 + threadIdx.x;
    float4 v = ((const float4*)evtX)[t];
    u16x4_t o;
    o.x = f2b(v.x); o.y = f2b(v.y); o.z = f2b(v.z); o.w = f2b(v.w);
    ((u16x4_t*)evtb)[t] = o;
  } else if (b < cvtBlocks + 448) {
    int t = (b - cvtBlocks) * 256 + threadIdx.x;  // [0, 114688)
    const float* src; int o;
    if (t < 16384)      { src = Wp; o = t; }
    else if (t < 65536) { src = Wi; o = t - 16384; }
    else                { src = Wh; o = t - 65536; }
    float4 v = ((const float4*)src)[o];
    u16x4_t q;
    q.x = f2b(v.x); q.y = f2b(v.y); q.z = f2b(v.z); q.w = f2b(v.w);
    ((u16x4_t*)wb)[t] = q;
  } else {
    int t = (b - cvtBlocks - 448) * 256 + threadIdx.x;
    if (t < nMain) {
      int o = main_idx[t];
      if (atomicCAS(&mask[o], 0, 1) == 0) {
        int i = atomicAdd(mcount, 1);
        mlist[i] = o;
        cpos[o] = i;
      }
    }
  }
}

// ---------------- masked degree count ----------------
__global__ void count_edges(const int* __restrict__ obj_idx, const int* __restrict__ mask,
                            int* __restrict__ deg, int n) {
  int e = blockIdx.x * 256 + threadIdx.x;
  if (e >= n) return;
  int o = obj_idx[e];
  if (mask[o]) atomicAdd(&deg[o], 1);
}

// ---------------- segment allocation: wave-scan + one atomic per wave; also builds rrows ----------------
__global__ __launch_bounds__(256)
void alloc_offs(const int* __restrict__ mlist, const int* __restrict__ mcount,
                const int* __restrict__ deg, int* __restrict__ offs,
                int* __restrict__ tcur, int* __restrict__ rrows, int Mpad) {
  int i = blockIdx.x * 256 + threadIdx.x;
  int lane = threadIdx.x & 63;
  int mc = *mcount;
  if (i < Mpad) rrows[i] = (i < mc) ? mlist[i] : 0;
  int o = (i < mc) ? mlist[i] : 0;
  int d = (i < mc) ? deg[o] : 0;
  int x = d;
#pragma unroll
  for (int s = 1; s < 64; s <<= 1) {
    int y = __shfl_up(x, s, 64);
    if (lane >= s) x += y;
  }
  int wt = __shfl(x, 63, 64);
  int base = 0;
  if (lane == 63 && wt > 0) base = atomicAdd(tcur, wt);
  base = __shfl(base, 63, 64);
  if (i < mc) offs[o] = base + (x - d);
}

__global__ void fill_edges(const int* __restrict__ obj_idx, const int* __restrict__ evt_idx,
                           const int* __restrict__ mask, const int* __restrict__ offs,
                           int* __restrict__ cursor, int* __restrict__ elist, int n) {
  int e = blockIdx.x * 256 + threadIdx.x;
  if (e >= n) return;
  int o = obj_idx[e];
  if (!mask[o]) return;
  int pos = atomicAdd(&cursor[o], 1);
  elist[offs[o] + pos] = evt_idx[e];
}

// ---------------- fused: profile scatter-mean accumulation + objX gather/cvt ----------------
__global__ __launch_bounds__(256)
void accum_gather(const u16* __restrict__ P, const int* __restrict__ elist,
                  const int* __restrict__ offs, const int* __restrict__ deg,
                  const int* __restrict__ mlist, const int* __restrict__ mcount,
                  const float* __restrict__ objX, const int* __restrict__ rrows,
                  u16* __restrict__ prof, u16* __restrict__ objc, int Mpad) {
  const int wave = threadIdx.x >> 6;
  const int lane = threadIdx.x & 63;
  const int i = blockIdx.x * 4 + wave;
  if (i >= Mpad) return;

  // gather objX row (issue loads early; independent of accum below)
  int src = rrows[i];
  float4 xv = *(const float4*)(objX + (size_t)src * 256 + lane * 4);

  const int mc = *mcount;
  float a0 = 0.f, a1 = 0.f, a2 = 0.f, a3 = 0.f;
  int d = 0;
  if (i < mc) {
    const int o = mlist[i];
    const int off = offs[o];
    d = deg[o];
    int j = 0;
    for (; j + 1 < d; j += 2) {
      int e0 = elist[off + j], e1 = elist[off + j + 1];
      u16x4_t p0 = *(const u16x4_t*)(P + (size_t)e0 * 256 + lane * 4);
      u16x4_t p1 = *(const u16x4_t*)(P + (size_t)e1 * 256 + lane * 4);
      a0 += b2f(p0.x) + b2f(p1.x);
      a1 += b2f(p0.y) + b2f(p1.y);
      a2 += b2f(p0.z) + b2f(p1.z);
      a3 += b2f(p0.w) + b2f(p1.w);
    }
    if (j < d) {
      int e0 = elist[off + j];
      u16x4_t p0 = *(const u16x4_t*)(P + (size_t)e0 * 256 + lane * 4);
      a0 += b2f(p0.x); a1 += b2f(p0.y); a2 += b2f(p0.z); a3 += b2f(p0.w);
    }
  }
  float s = 1.f / fmaxf((float)d, 1.f);
  u16x4_t pv;
  pv.x = f2b(a0 * s); pv.y = f2b(a1 * s); pv.z = f2b(a2 * s); pv.w = f2b(a3 * s);
  *(u16x4_t*)(prof + (size_t)i * 256 + lane * 4) = pv;

  u16x4_t ov;
  ov.x = f2b(xv.x); ov.y = f2b(xv.y); ov.z = f2b(xv.z); ov.w = f2b(xv.w);
  *(u16x4_t*)(objc + (size_t)i * 256 + lane * 4) = ov;
}

// ---------------- LDS-free MFMA GEMM core ----------------
// K=256 is a single pass and B is L2-resident (<=393KB), so skip LDS staging
// entirely: each wave loads its MFMA fragments straight from global.
// Fragment load = 16 rows x 16B @ stride 512B; quarter-waves cover bytes
// 0..63 of each 64B line -> 16 fully-used lines per instruction (same
// transaction count as ideal contiguous coalescing). No barriers, no
// vmcnt(0) drain, no bank conflicts, no LDS occupancy cap.
template<int RELU>
__device__ __forceinline__
void gemm_core(const u16* __restrict__ A, const u16* __restrict__ B,
               const float* __restrict__ bias, u16* __restrict__ C,
               int M, int N, int n0, int m0) {
  const int lane = threadIdx.x & 63;
  const int wave = threadIdx.x >> 6;
  const int mR = (wave & 1) * 64;
  const int nC = (wave >> 1) * 64;
  const int lr = lane & 15;          // row within fragment
  const int koff = (lane >> 4) * 8;  // k-chunk within K=32 step

  const u16* pa[4];
  const u16* pb[4];
#pragma unroll
  for (int i = 0; i < 4; ++i) {
    int ar = m0 + mR + i * 16 + lr;
    ar = (ar < M) ? ar : (M - 1);
    pa[i] = A + (size_t)ar * 256 + koff;
    pb[i] = B + (size_t)(n0 + nC + i * 16 + lr) * 256 + koff;
  }

  f32x4 acc[4][4] = {};
#pragma unroll
  for (int kt = 0; kt < 256; kt += 32) {
    bf16x8 af[4], bf[4];
#pragma unroll
    for (int i = 0; i < 4; ++i) af[i] = *(const bf16x8*)(pa[i] + kt);
#pragma unroll
    for (int j = 0; j < 4; ++j) bf[j] = *(const bf16x8*)(pb[j] + kt);
#pragma unroll
    for (int i = 0; i < 4; ++i)
#pragma unroll
      for (int j = 0; j < 4; ++j)
        acc[i][j] = __builtin_amdgcn_mfma_f32_16x16x32_bf16(af[i], bf[j], acc[i][j], 0, 0, 0);
  }

  // C/D layout: col=lane&15, row=(lane>>4)*4+reg (verified m89/m91)
  const int crow = (lane >> 4) * 4;
  const int ccol = lane & 15;
#pragma unroll
  for (int i = 0; i < 4; ++i) {
#pragma unroll
    for (int j = 0; j < 4; ++j) {
      int col = n0 + nC + j * 16 + ccol;
      float bv = bias[col];
#pragma unroll
      for (int q = 0; q < 4; ++q) {
        int row = m0 + mR + i * 16 + crow + q;
        if (row < M) {
          float v = acc[i][j][q] + bv;
          if (RELU) v = fmaxf(v, 0.f);
          C[(size_t)row * N + col] = f2b(v);
        }
      }
    }
  }
}

__global__ __launch_bounds__(256, 3)
void gemm_p(const u16* __restrict__ A, const u16* __restrict__ B,
            const float* __restrict__ bias, u16* __restrict__ C, int M) {
  gemm_core<1>(A, B, bias, C, M, 256, blockIdx.y * 128, blockIdx.x * 128);
}

// both GRU GEMMs in one dispatch, 1-D grid with bijective XCD swizzle:
// the 12 n-tiles (6 gi + 6 gh) of one 128-row panel land on the same XCD,
// so prof/objc row-panels are read from that XCD's L2 instead of HBM.
__global__ __launch_bounds__(256, 3)
void gemm2_dual(const u16* __restrict__ prof, const u16* __restrict__ objc,
                const u16* __restrict__ wib, const u16* __restrict__ whb,
                const float* __restrict__ bi, const float* __restrict__ bh,
                u16* __restrict__ gi, u16* __restrict__ gh, int Mpad, int nwg) {
  int bid = blockIdx.x;
  int q = nwg >> 3, r = nwg & 7;
  int xcd = bid & 7, loc = bid >> 3;
  int wg = (xcd < r ? xcd * (q + 1) : r * (q + 1) + (xcd - r) * q) + loc;
  int m0 = (wg / 12) * 128;
  int y = wg % 12;
  if (y < 6) gemm_core<0>(prof, wib, bi, gi, Mpad, 768, y * 128, m0);
  else       gemm_core<0>(objc, whb, bh, gh, Mpad, 768, (y - 6) * 128, m0);
}

// ---------------- GRU gates + masked blend (float4-vectorized; 4 rows / block) ----------------
__global__ __launch_bounds__(256)
void gate_out(const u16* __restrict__ gi, const u16* __restrict__ gh,
              const float* __restrict__ objX, const int* __restrict__ mask,
              const int* __restrict__ cpos, float* __restrict__ out, int nObj) {
  const int wave = threadIdx.x >> 6;
  const int lane = threadIdx.x & 63;
  const int row = blockIdx.x * 4 + wave;
  if (row >= nObj) return;
  float4 x4 = *(const float4*)(objX + (size_t)row * 256 + lane * 4);
  float4 r4 = x4;
  if (mask[row]) {
    size_t b = (size_t)cpos[row] * 768 + lane * 4;
    u16x4_t ir = *(const u16x4_t*)(gi + b);
    u16x4_t iz = *(const u16x4_t*)(gi + b + 256);
    u16x4_t in_ = *(const u16x4_t*)(gi + b + 512);
    u16x4_t hr = *(const u16x4_t*)(gh + b);
    u16x4_t hz = *(const u16x4_t*)(gh + b + 256);
    u16x4_t hn = *(const u16x4_t*)(gh + b + 512);
    float xs[4] = {x4.x, x4.y, x4.z, x4.w};
    u16 irs[4] = {ir.x, ir.y, ir.z, ir.w};
    u16 izs[4] = {iz.x, iz.y, iz.z, iz.w};
    u16 ins[4] = {in_.x, in_.y, in_.z, in_.w};
    u16 hrs[4] = {hr.x, hr.y, hr.z, hr.w};
    u16 hzs[4] = {hz.x, hz.y, hz.z, hz.w};
    u16 hns[4] = {hn.x, hn.y, hn.z, hn.w};
    float rs[4];
#pragma unroll
    for (int q = 0; q < 4; ++q) {
      float r = 1.f / (1.f + __expf(-(b2f(irs[q]) + b2f(hrs[q]))));
      float z = 1.f / (1.f + __expf(-(b2f(izs[q]) + b2f(hzs[q]))));
      float a = b2f(ins[q]) + r * b2f(hns[q]);
      float n = 1.f - 2.f / (__expf(2.f * a) + 1.f);
      rs[q] = (1.f - z) * n + z * xs[q];
    }
    r4.x = rs[0]; r4.y = rs[1]; r4.z = rs[2]; r4.w = rs[3];
  }
  *(float4*)(out + (size_t)row * 256 + lane * 4) = r4;
}

// ---------------- workspace layout (bytes) ----------------
//           0  P      51,200,000  (dead after accum_gather) -> gi reuse
//  51,200,000  gh     38,535,168
//  89,735,168  prof   12,845,056
// 102,580,224  objc   12,845,056
// 115,425,280  evtb   51,200,000  (dead after gemm_p)
// 166,625,280  wb        917,504  (wpb|wib|whb)
// 167,542,784  deg       200,000  \
// 167,742,784  cursor    200,000   |  one memset zeroes
// 167,942,784  mask      200,000   |  [167,542,784 .. 168,142,912)
// 168,142,784  mcount         64   |
// 168,142,848  tcur           64  /
// 168,142,912  cpos      200,000
// 168,342,912  offs      200,000
// 168,542,912  mlist     100,352
// 168,643,264  rrows     100,352
// 168,743,616  elist   2,000,000
// total 170,743,616

extern "C" void kernel_launch(void* const* d_in, const int* in_sizes, int n_in,
                              void* d_out, int out_size, void* d_ws, size_t ws_size,
                              hipStream_t stream) {
  const float* objX   = (const float*)d_in[0];
  const float* evtX   = (const float*)d_in[1];
  const int* obj_idx  = (const int*)d_in[2];
  const int* evt_idx  = (const int*)d_in[3];
  const int* main_idx = (const int*)d_in[4];
  const float* Wp = (const float*)d_in[5];
  const float* bp = (const float*)d_in[6];
  const float* Wi = (const float*)d_in[7];
  const float* bi = (const float*)d_in[8];
  const float* Wh = (const float*)d_in[9];
  const float* bh = (const float*)d_in[10];

  const int nObj  = in_sizes[0] / 256;   // 50000
  const int nEvt  = in_sizes[1] / 256;   // 100000
  const int nEdge = in_sizes[2];         // 500000
  const int nMain = in_sizes[4];         // 25000
  const int Mpad  = ((nMain + 127) / 128) * 128;  // 25088

  char* ws = (char*)d_ws;
  u16*   P     = (u16*)(ws + 0);
  u16*   gi    = (u16*)(ws + 0);
  u16*   gh    = (u16*)(ws + 51200000);
  u16*   prof  = (u16*)(ws + 89735168);
  u16*   objc  = (u16*)(ws + 102580224);
  u16*   evtb  = (u16*)(ws + 115425280);
  u16*   wb    = (u16*)(ws + 166625280);
  u16*   wpb   = wb;
  u16*   wib   = wb + 65536;
  u16*   whb   = wb + 262144;
  int*   deg   = (int*)(ws + 167542784);
  int*   cursor= (int*)(ws + 167742784);
  int*   mask  = (int*)(ws + 167942784);
  int*   mcount= (int*)(ws + 168142784);
  int*   tcur  = (int*)(ws + 168142848);
  int*   cpos  = (int*)(ws + 168142912);
  int*   offs  = (int*)(ws + 168342912);
  int*   mlist = (int*)(ws + 168542912);
  int*   rrows = (int*)(ws + 168643264);
  int*   elist = (int*)(ws + 168743616);
  float* out   = (float*)d_out;

  hipMemsetAsync(ws + 167542784, 0, 600128, stream);

  const int nEvtF4 = in_sizes[1] / 4;                       // 6,400,000
  const int prepGrid = nEvtF4 / 256 + 448 + (nMain + 255) / 256;  // 25546
  prep<<<prepGrid, 256, 0, stream>>>(evtX, evtb, nEvtF4, Wp, Wi, Wh, wb,
                                     main_idx, mask, mlist, cpos, mcount, nMain);

  // P = relu(evtb @ Wp^T + bp)  [100000 x 256]
  gemm_p<<<dim3((nEvt + 127) / 128, 2), 256, 0, stream>>>(evtb, wpb, bp, P, nEvt);

  count_edges<<<(nEdge + 255) / 256, 256, 0, stream>>>(obj_idx, mask, deg, nEdge);
  alloc_offs<<<Mpad / 256, 256, 0, stream>>>(mlist, mcount, deg, offs, tcur, rrows, Mpad);
  fill_edges<<<(nEdge + 255) / 256, 256, 0, stream>>>(obj_idx, evt_idx, mask, offs, cursor, elist, nEdge);

  accum_gather<<<(Mpad + 3) / 4, 256, 0, stream>>>(P, elist, offs, deg, mlist, mcount,
                                                   objX, rrows, prof, objc, Mpad);

  // gi = prof @ Wi^T + bi ; gh = objc @ Wh^T + bh  [25088 x 768], one dispatch
  const int nwg = (Mpad / 128) * 12;
  gemm2_dual<<<nwg, 256, 0, stream>>>(prof, objc, wib, whb, bi, bh, gi, gh, Mpad, nwg);

  gate_out<<<(nObj + 3) / 4, 256, 0, stream>>>(gi, gh, objX, mask, cpos, out, nObj);
}

// Round 3
// 389.769 us; speedup vs baseline: 1.1522x; 1.1522x over previous
//
#include <hip/hip_runtime.h>

typedef unsigned short u16;
typedef __attribute__((ext_vector_type(8))) short bf16x8;
typedef __attribute__((ext_vector_type(4))) float f32x4;

struct __align__(8) u16x4_t { u16 x, y, z, w; };

__device__ __forceinline__ float b2f(u16 b) {
  union { unsigned u; float f; } v; v.u = ((unsigned)b) << 16; return v.f;
}
__device__ __forceinline__ u16 f2b(float f) {
  union { float f; unsigned u; } v; v.f = f;
  unsigned r = v.u + 0x7fffu + ((v.u >> 16) & 1u);
  return (u16)(r >> 16);
}

// ---------------- prep: evtX cvt + weight cvt + mask/mlist build, one dispatch ----------------
__global__ void prep(const float* __restrict__ evtX, u16* __restrict__ evtb, int nEvtF4,
                     const float* __restrict__ Wp, const float* __restrict__ Wi,
                     const float* __restrict__ Wh, u16* __restrict__ wb,
                     const int* __restrict__ main_idx, int* __restrict__ mask,
                     int* __restrict__ mlist, int* __restrict__ cpos,
                     int* __restrict__ mcount, int nMain) {
  const int cvtBlocks = nEvtF4 / 256;           // 25000
  int b = blockIdx.x;
  if (b < cvtBlocks) {
    int t = b * 256 + threadIdx.x;
    float4 v = ((const float4*)evtX)[t];
    u16x4_t o;
    o.x = f2b(v.x); o.y = f2b(v.y); o.z = f2b(v.z); o.w = f2b(v.w);
    ((u16x4_t*)evtb)[t] = o;
  } else if (b < cvtBlocks + 448) {
    int t = (b - cvtBlocks) * 256 + threadIdx.x;  // [0, 114688)
    const float* src; int o;
    if (t < 16384)      { src = Wp; o = t; }
    else if (t < 65536) { src = Wi; o = t - 16384; }
    else                { src = Wh; o = t - 65536; }
    float4 v = ((const float4*)src)[o];
    u16x4_t q;
    q.x = f2b(v.x); q.y = f2b(v.y); q.z = f2b(v.z); q.w = f2b(v.w);
    ((u16x4_t*)wb)[t] = q;
  } else {
    int t = (b - cvtBlocks - 448) * 256 + threadIdx.x;
    if (t < nMain) {
      int o = main_idx[t];
      if (atomicCAS(&mask[o], 0, 1) == 0) {
        int i = atomicAdd(mcount, 1);
        mlist[i] = o;
        cpos[o] = i;
      }
    }
  }
}

// ---------------- masked degree count ----------------
__global__ void count_edges(const int* __restrict__ obj_idx, const int* __restrict__ mask,
                            int* __restrict__ deg, int n) {
  int e = blockIdx.x * 256 + threadIdx.x;
  if (e >= n) return;
  int o = obj_idx[e];
  if (mask[o]) atomicAdd(&deg[o], 1);
}

// ---------------- segment allocation: wave-scan + one atomic per wave; also builds rrows ----------------
__global__ __launch_bounds__(256)
void alloc_offs(const int* __restrict__ mlist, const int* __restrict__ mcount,
                const int* __restrict__ deg, int* __restrict__ offs,
                int* __restrict__ tcur, int* __restrict__ rrows, int Mpad) {
  int i = blockIdx.x * 256 + threadIdx.x;
  int lane = threadIdx.x & 63;
  int mc = *mcount;
  if (i < Mpad) rrows[i] = (i < mc) ? mlist[i] : 0;
  int o = (i < mc) ? mlist[i] : 0;
  int d = (i < mc) ? deg[o] : 0;
  int x = d;
#pragma unroll
  for (int s = 1; s < 64; s <<= 1) {
    int y = __shfl_up(x, s, 64);
    if (lane >= s) x += y;
  }
  int wt = __shfl(x, 63, 64);
  int base = 0;
  if (lane == 63 && wt > 0) base = atomicAdd(tcur, wt);
  base = __shfl(base, 63, 64);
  if (i < mc) offs[o] = base + (x - d);
}

__global__ void fill_edges(const int* __restrict__ obj_idx, const int* __restrict__ evt_idx,
                           const int* __restrict__ mask, const int* __restrict__ offs,
                           int* __restrict__ cursor, int* __restrict__ elist, int n) {
  int e = blockIdx.x * 256 + threadIdx.x;
  if (e >= n) return;
  int o = obj_idx[e];
  if (!mask[o]) return;
  int pos = atomicAdd(&cursor[o], 1);
  elist[offs[o] + pos] = evt_idx[e];
}

// ---------------- fused: profile scatter-mean accumulation + objX gather/cvt ----------------
__global__ __launch_bounds__(256)
void accum_gather(const u16* __restrict__ P, const int* __restrict__ elist,
                  const int* __restrict__ offs, const int* __restrict__ deg,
                  const int* __restrict__ mlist, const int* __restrict__ mcount,
                  const float* __restrict__ objX, const int* __restrict__ rrows,
                  u16* __restrict__ prof, u16* __restrict__ objc, int Mpad) {
  const int wave = threadIdx.x >> 6;
  const int lane = threadIdx.x & 63;
  const int i = blockIdx.x * 4 + wave;
  if (i >= Mpad) return;

  // gather objX row (issue loads early; independent of accum below)
  int src = rrows[i];
  float4 xv = *(const float4*)(objX + (size_t)src * 256 + lane * 4);

  const int mc = *mcount;
  float a0 = 0.f, a1 = 0.f, a2 = 0.f, a3 = 0.f;
  int d = 0;
  if (i < mc) {
    const int o = mlist[i];
    const int off = offs[o];
    d = deg[o];
    int j = 0;
    for (; j + 1 < d; j += 2) {
      int e0 = elist[off + j], e1 = elist[off + j + 1];
      u16x4_t p0 = *(const u16x4_t*)(P + (size_t)e0 * 256 + lane * 4);
      u16x4_t p1 = *(const u16x4_t*)(P + (size_t)e1 * 256 + lane * 4);
      a0 += b2f(p0.x) + b2f(p1.x);
      a1 += b2f(p0.y) + b2f(p1.y);
      a2 += b2f(p0.z) + b2f(p1.z);
      a3 += b2f(p0.w) + b2f(p1.w);
    }
    if (j < d) {
      int e0 = elist[off + j];
      u16x4_t p0 = *(const u16x4_t*)(P + (size_t)e0 * 256 + lane * 4);
      a0 += b2f(p0.x); a1 += b2f(p0.y); a2 += b2f(p0.z); a3 += b2f(p0.w);
    }
  }
  float s = 1.f / fmaxf((float)d, 1.f);
  u16x4_t pv;
  pv.x = f2b(a0 * s); pv.y = f2b(a1 * s); pv.z = f2b(a2 * s); pv.w = f2b(a3 * s);
  *(u16x4_t*)(prof + (size_t)i * 256 + lane * 4) = pv;

  u16x4_t ov;
  ov.x = f2b(xv.x); ov.y = f2b(xv.y); ov.z = f2b(xv.z); ov.w = f2b(xv.w);
  *(u16x4_t*)(objc + (size_t)i * 256 + lane * 4) = ov;
}

// ---------------- pipelined MFMA GEMM core (T3-minimum 2-phase + T2 swizzle) ----------------
// 128x128 tile, BK=64, double-buffered LDS (64 KB). Per K-tile: issue next
// tile's global_load_lds BEFORE ds_read+MFMA of current (loads hide under
// compute), ONE barrier per tile. LDS is XOR-swizzled both-sides (rule 21):
// dest stays linear (global_load_lds requirement), the global SOURCE k-offset
// is pre-swizzled kq = (g&7)^(row&7), and ds_read applies the same involution
// -> 2-way bank aliasing (free, m136) instead of 16-way.
template<int RELU>
__device__ __forceinline__
void gemm_core(const u16* __restrict__ A, const u16* __restrict__ B,
               const float* __restrict__ bias, u16* __restrict__ C,
               int M, int N, int n0, int m0, u16* lA, u16* lB) {
  const int tid  = threadIdx.x;
  const int lane = tid & 63;
  const int wave = tid >> 6;
  const int mR = (wave & 1) * 64;
  const int nC = (wave >> 1) * 64;

  // staging geometry: physical 16B-granule g = s*256 + tid covers
  // row = g>>3, swizzled logical k-offset = ((g&7)^(row&7))*8 elements.
  int srow[4], skq[4];
#pragma unroll
  for (int s = 0; s < 4; ++s) {
    int g = s * 256 + tid;
    srow[s] = g >> 3;
    skq[s]  = ((g & 7) ^ ((g >> 3) & 7)) << 3;
  }

  f32x4 acc[4][4] = {};

  auto STAGE = [&](int buf, int kt) {
#pragma unroll
    for (int s = 0; s < 4; ++s) {
      int row = srow[s];
      int ar = m0 + row; ar = (ar < M) ? ar : (M - 1);
      const u16* gA = A + (size_t)ar * 256 + kt + skq[s];
      __builtin_amdgcn_global_load_lds(
          (const __attribute__((address_space(1))) void*)gA,
          (__attribute__((address_space(3))) void*)(lA + buf * 8192 + s * 2048 + wave * 512),
          16, 0, 0);
      const u16* gB = B + (size_t)(n0 + row) * 256 + kt + skq[s];
      __builtin_amdgcn_global_load_lds(
          (const __attribute__((address_space(1))) void*)gB,
          (__attribute__((address_space(3))) void*)(lB + buf * 8192 + s * 2048 + wave * 512),
          16, 0, 0);
    }
  };

  STAGE(0, 0);
  __syncthreads();  // drain vmcnt(0) then barrier: buf0 ready

  for (int t = 0; t < 4; ++t) {
    const int cur = t & 1;
    if (t < 3) STAGE(cur ^ 1, (t + 1) * 64);  // prefetch: flies under compute below
    const u16* bA = lA + cur * 8192;
    const u16* bB = lB + cur * 8192;
#pragma unroll
    for (int ks = 0; ks < 2; ++ks) {
      const int kbq = ks * 4 + (lane >> 4);  // logical granule 0..7 within row
      bf16x8 af[4], bf[4];
#pragma unroll
      for (int i = 0; i < 4; ++i) {
        int ra = mR + i * 16 + (lane & 15);
        af[i] = *(const bf16x8*)(bA + ra * 64 + ((kbq ^ (ra & 7)) << 3));
        int rb = nC + i * 16 + (lane & 15);
        bf[i] = *(const bf16x8*)(bB + rb * 64 + ((kbq ^ (rb & 7)) << 3));
      }
#pragma unroll
      for (int i = 0; i < 4; ++i)
#pragma unroll
        for (int j = 0; j < 4; ++j)
          acc[i][j] = __builtin_amdgcn_mfma_f32_16x16x32_bf16(af[i], bf[j], acc[i][j], 0, 0, 0);
    }
    // one barrier per tile: drains prefetch (needed next iter) + protects
    // buf[cur] from being overwritten while still being read (reads done above)
    __syncthreads();
  }

  // C/D layout: col=lane&15, row=(lane>>4)*4+reg (verified m89/m91)
  const int crow = (lane >> 4) * 4;
  const int ccol = lane & 15;
#pragma unroll
  for (int i = 0; i < 4; ++i) {
#pragma unroll
    for (int j = 0; j < 4; ++j) {
      int col = n0 + nC + j * 16 + ccol;
      float bv = bias[col];
#pragma unroll
      for (int q = 0; q < 4; ++q) {
        int row = m0 + mR + i * 16 + crow + q;
        if (row < M) {
          float v = acc[i][j][q] + bv;
          if (RELU) v = fmaxf(v, 0.f);
          C[(size_t)row * N + col] = f2b(v);
        }
      }
    }
  }
}

// bijective XCD swizzle (m204): consecutive wg land on one XCD's chunk
__device__ __forceinline__ int xcd_swz(int bid, int nwg) {
  int q = nwg >> 3, r = nwg & 7;
  int xcd = bid & 7, loc = bid >> 3;
  return (xcd < r ? xcd * (q + 1) : r * (q + 1) + (xcd - r) * q) + loc;
}

// P-GEMM: the 2 n-tiles of each 128-row A-panel are consecutive wg -> same XCD L2
__global__ __launch_bounds__(256, 2)
void gemm_p(const u16* __restrict__ A, const u16* __restrict__ B,
            const float* __restrict__ bias, u16* __restrict__ C, int M, int nwg) {
  __shared__ u16 lA[2 * 8192];
  __shared__ u16 lB[2 * 8192];
  int wg = xcd_swz(blockIdx.x, nwg);
  gemm_core<1>(A, B, bias, C, M, 256, (wg & 1) * 128, (wg >> 1) * 128, lA, lB);
}

// both GRU GEMMs in one dispatch: the 12 n-tiles (6 gi + 6 gh) of one
// 128-row panel are consecutive wg -> same XCD L2 (proven: FETCH 64->20 MB)
__global__ __launch_bounds__(256, 2)
void gemm2_dual(const u16* __restrict__ prof, const u16* __restrict__ objc,
                const u16* __restrict__ wib, const u16* __restrict__ whb,
                const float* __restrict__ bi, const float* __restrict__ bh,
                u16* __restrict__ gi, u16* __restrict__ gh, int Mpad, int nwg) {
  __shared__ u16 lA[2 * 8192];
  __shared__ u16 lB[2 * 8192];
  int wg = xcd_swz(blockIdx.x, nwg);
  int m0 = (wg / 12) * 128;
  int y = wg % 12;
  if (y < 6) gemm_core<0>(prof, wib, bi, gi, Mpad, 768, y * 128, m0, lA, lB);
  else       gemm_core<0>(objc, whb, bh, gh, Mpad, 768, (y - 6) * 128, m0, lA, lB);
}

// ---------------- GRU gates + masked blend (float4-vectorized; 4 rows / block) ----------------
__global__ __launch_bounds__(256)
void gate_out(const u16* __restrict__ gi, const u16* __restrict__ gh,
              const float* __restrict__ objX, const int* __restrict__ mask,
              const int* __restrict__ cpos, float* __restrict__ out, int nObj) {
  const int wave = threadIdx.x >> 6;
  const int lane = threadIdx.x & 63;
  const int row = blockIdx.x * 4 + wave;
  if (row >= nObj) return;
  float4 x4 = *(const float4*)(objX + (size_t)row * 256 + lane * 4);
  float4 r4 = x4;
  if (mask[row]) {
    size_t b = (size_t)cpos[row] * 768 + lane * 4;
    u16x4_t ir = *(const u16x4_t*)(gi + b);
    u16x4_t iz = *(const u16x4_t*)(gi + b + 256);
    u16x4_t in_ = *(const u16x4_t*)(gi + b + 512);
    u16x4_t hr = *(const u16x4_t*)(gh + b);
    u16x4_t hz = *(const u16x4_t*)(gh + b + 256);
    u16x4_t hn = *(const u16x4_t*)(gh + b + 512);
    float xs[4] = {x4.x, x4.y, x4.z, x4.w};
    u16 irs[4] = {ir.x, ir.y, ir.z, ir.w};
    u16 izs[4] = {iz.x, iz.y, iz.z, iz.w};
    u16 ins[4] = {in_.x, in_.y, in_.z, in_.w};
    u16 hrs[4] = {hr.x, hr.y, hr.z, hr.w};
    u16 hzs[4] = {hz.x, hz.y, hz.z, hz.w};
    u16 hns[4] = {hn.x, hn.y, hn.z, hn.w};
    float rs[4];
#pragma unroll
    for (int q = 0; q < 4; ++q) {
      float r = 1.f / (1.f + __expf(-(b2f(irs[q]) + b2f(hrs[q]))));
      float z = 1.f / (1.f + __expf(-(b2f(izs[q]) + b2f(hzs[q]))));
      float a = b2f(ins[q]) + r * b2f(hns[q]);
      float n = 1.f - 2.f / (__expf(2.f * a) + 1.f);
      rs[q] = (1.f - z) * n + z * xs[q];
    }
    r4.x = rs[0]; r4.y = rs[1]; r4.z = rs[2]; r4.w = rs[3];
  }
  *(float4*)(out + (size_t)row * 256 + lane * 4) = r4;
}

// ---------------- workspace layout (bytes) ----------------
//           0  P      51,200,000  (dead after accum_gather) -> gi reuse
//  51,200,000  gh     38,535,168
//  89,735,168  prof   12,845,056
// 102,580,224  objc   12,845,056
// 115,425,280  evtb   51,200,000  (dead after gemm_p)
// 166,625,280  wb        917,504  (wpb|wib|whb)
// 167,542,784  deg       200,000  \
// 167,742,784  cursor    200,000   |  one memset zeroes
// 167,942,784  mask      200,000   |  [167,542,784 .. 168,142,912)
// 168,142,784  mcount         64   |
// 168,142,848  tcur           64  /
// 168,142,912  cpos      200,000
// 168,342,912  offs      200,000
// 168,542,912  mlist     100,352
// 168,643,264  rrows     100,352
// 168,743,616  elist   2,000,000
// total 170,743,616

extern "C" void kernel_launch(void* const* d_in, const int* in_sizes, int n_in,
                              void* d_out, int out_size, void* d_ws, size_t ws_size,
                              hipStream_t stream) {
  const float* objX   = (const float*)d_in[0];
  const float* evtX   = (const float*)d_in[1];
  const int* obj_idx  = (const int*)d_in[2];
  const int* evt_idx  = (const int*)d_in[3];
  const int* main_idx = (const int*)d_in[4];
  const float* Wp = (const float*)d_in[5];
  const float* bp = (const float*)d_in[6];
  const float* Wi = (const float*)d_in[7];
  const float* bi = (const float*)d_in[8];
  const float* Wh = (const float*)d_in[9];
  const float* bh = (const float*)d_in[10];

  const int nObj  = in_sizes[0] / 256;   // 50000
  const int nEvt  = in_sizes[1] / 256;   // 100000
  const int nEdge = in_sizes[2];         // 500000
  const int nMain = in_sizes[4];         // 25000
  const int Mpad  = ((nMain + 127) / 128) * 128;  // 25088

  char* ws = (char*)d_ws;
  u16*   P     = (u16*)(ws + 0);
  u16*   gi    = (u16*)(ws + 0);
  u16*   gh    = (u16*)(ws + 51200000);
  u16*   prof  = (u16*)(ws + 89735168);
  u16*   objc  = (u16*)(ws + 102580224);
  u16*   evtb  = (u16*)(ws + 115425280);
  u16*   wb    = (u16*)(ws + 166625280);
  u16*   wpb   = wb;
  u16*   wib   = wb + 65536;
  u16*   whb   = wb + 262144;
  int*   deg   = (int*)(ws + 167542784);
  int*   cursor= (int*)(ws + 167742784);
  int*   mask  = (int*)(ws + 167942784);
  int*   mcount= (int*)(ws + 168142784);
  int*   tcur  = (int*)(ws + 168142848);
  int*   cpos  = (int*)(ws + 168142912);
  int*   offs  = (int*)(ws + 168342912);
  int*   mlist = (int*)(ws + 168542912);
  int*   rrows = (int*)(ws + 168643264);
  int*   elist = (int*)(ws + 168743616);
  float* out   = (float*)d_out;

  hipMemsetAsync(ws + 167542784, 0, 600128, stream);

  const int nEvtF4 = in_sizes[1] / 4;                       // 6,400,000
  const int prepGrid = nEvtF4 / 256 + 448 + (nMain + 255) / 256;  // 25546
  prep<<<prepGrid, 256, 0, stream>>>(evtX, evtb, nEvtF4, Wp, Wi, Wh, wb,
                                     main_idx, mask, mlist, cpos, mcount, nMain);

  // P = relu(evtb @ Wp^T + bp)  [100000 x 256]
  const int nwgP = ((nEvt + 127) / 128) * 2;  // 1564
  gemm_p<<<nwgP, 256, 0, stream>>>(evtb, wpb, bp, P, nEvt, nwgP);

  count_edges<<<(nEdge + 255) / 256, 256, 0, stream>>>(obj_idx, mask, deg, nEdge);
  alloc_offs<<<Mpad / 256, 256, 0, stream>>>(mlist, mcount, deg, offs, tcur, rrows, Mpad);
  fill_edges<<<(nEdge + 255) / 256, 256, 0, stream>>>(obj_idx, evt_idx, mask, offs, cursor, elist, nEdge);

  accum_gather<<<(Mpad + 3) / 4, 256, 0, stream>>>(P, elist, offs, deg, mlist, mcount,
                                                   objX, rrows, prof, objc, Mpad);

  // gi = prof @ Wi^T + bi ; gh = objc @ Wh^T + bh  [25088 x 768], one dispatch
  const int nwg = (Mpad / 128) * 12;  // 2352
  gemm2_dual<<<nwg, 256, 0, stream>>>(prof, objc, wib, whb, bi, bh, gi, gh, Mpad, nwg);

  gate_out<<<(nObj + 3) / 4, 256, 0, stream>>>(gi, gh, objX, mask, cpos, out, nObj);
}

// Round 4
// 379.730 us; speedup vs baseline: 1.1827x; 1.0264x over previous
//
#include <hip/hip_runtime.h>

typedef unsigned short u16;
typedef __attribute__((ext_vector_type(8))) short bf16x8;
typedef __attribute__((ext_vector_type(4))) float f32x4;

struct __align__(8) u16x4_t { u16 x, y, z, w; };

__device__ __forceinline__ float b2f(u16 b) {
  union { unsigned u; float f; } v; v.u = ((unsigned)b) << 16; return v.f;
}
__device__ __forceinline__ u16 f2b(float f) {
  union { float f; unsigned u; } v; v.f = f;
  unsigned r = v.u + 0x7fffu + ((v.u >> 16) & 1u);
  return (u16)(r >> 16);
}
// RNE pack of two f32 into two bf16 (identical rounding to f2b)
__device__ __forceinline__ unsigned pk2(float lo, float hi) {
  unsigned r;
  asm("v_cvt_pk_bf16_f32 %0, %1, %2" : "=v"(r) : "v"(lo), "v"(hi));
  return r;
}

// ---------------- prep: weight cvt + mask/mlist build (evtX cvt now fused into gemm_pf) ----------------
__global__ void prep(const float* __restrict__ Wp, const float* __restrict__ Wi,
                     const float* __restrict__ Wh, u16* __restrict__ wb,
                     const int* __restrict__ main_idx, int* __restrict__ mask,
                     int* __restrict__ mlist, int* __restrict__ cpos,
                     int* __restrict__ mcount, int nMain) {
  int b = blockIdx.x;
  if (b < 448) {
    int t = b * 256 + threadIdx.x;  // [0, 114688)
    const float* src; int o;
    if (t < 16384)      { src = Wp; o = t; }
    else if (t < 65536) { src = Wi; o = t - 16384; }
    else                { src = Wh; o = t - 65536; }
    float4 v = ((const float4*)src)[o];
    u16x4_t q;
    q.x = f2b(v.x); q.y = f2b(v.y); q.z = f2b(v.z); q.w = f2b(v.w);
    ((u16x4_t*)wb)[t] = q;
  } else {
    int t = (b - 448) * 256 + threadIdx.x;
    if (t < nMain) {
      int o = main_idx[t];
      if (atomicCAS(&mask[o], 0, 1) == 0) {
        int i = atomicAdd(mcount, 1);
        mlist[i] = o;
        cpos[o] = i;
      }
    }
  }
}

// ---------------- masked degree count ----------------
__global__ void count_edges(const int* __restrict__ obj_idx, const int* __restrict__ mask,
                            int* __restrict__ deg, int n) {
  int e = blockIdx.x * 256 + threadIdx.x;
  if (e >= n) return;
  int o = obj_idx[e];
  if (mask[o]) atomicAdd(&deg[o], 1);
}

// ---------------- segment allocation: wave-scan + one atomic per wave; also builds rrows ----------------
__global__ __launch_bounds__(256)
void alloc_offs(const int* __restrict__ mlist, const int* __restrict__ mcount,
                const int* __restrict__ deg, int* __restrict__ offs,
                int* __restrict__ tcur, int* __restrict__ rrows, int Mpad) {
  int i = blockIdx.x * 256 + threadIdx.x;
  int lane = threadIdx.x & 63;
  int mc = *mcount;
  if (i < Mpad) rrows[i] = (i < mc) ? mlist[i] : 0;
  int o = (i < mc) ? mlist[i] : 0;
  int d = (i < mc) ? deg[o] : 0;
  int x = d;
#pragma unroll
  for (int s = 1; s < 64; s <<= 1) {
    int y = __shfl_up(x, s, 64);
    if (lane >= s) x += y;
  }
  int wt = __shfl(x, 63, 64);
  int base = 0;
  if (lane == 63 && wt > 0) base = atomicAdd(tcur, wt);
  base = __shfl(base, 63, 64);
  if (i < mc) offs[o] = base + (x - d);
}

__global__ void fill_edges(const int* __restrict__ obj_idx, const int* __restrict__ evt_idx,
                           const int* __restrict__ mask, const int* __restrict__ offs,
                           int* __restrict__ cursor, int* __restrict__ elist, int n) {
  int e = blockIdx.x * 256 + threadIdx.x;
  if (e >= n) return;
  int o = obj_idx[e];
  if (!mask[o]) return;
  int pos = atomicAdd(&cursor[o], 1);
  elist[offs[o] + pos] = evt_idx[e];
}

// ---------------- fused: profile scatter-mean accumulation + objX gather/cvt ----------------
__global__ __launch_bounds__(256)
void accum_gather(const u16* __restrict__ P, const int* __restrict__ elist,
                  const int* __restrict__ offs, const int* __restrict__ deg,
                  const int* __restrict__ mlist, const int* __restrict__ mcount,
                  const float* __restrict__ objX, const int* __restrict__ rrows,
                  u16* __restrict__ prof, u16* __restrict__ objc, int Mpad) {
  const int wave = threadIdx.x >> 6;
  const int lane = threadIdx.x & 63;
  const int i = blockIdx.x * 4 + wave;
  if (i >= Mpad) return;

  // gather objX row (issue loads early; independent of accum below)
  int src = rrows[i];
  float4 xv = *(const float4*)(objX + (size_t)src * 256 + lane * 4);

  const int mc = *mcount;
  float a0 = 0.f, a1 = 0.f, a2 = 0.f, a3 = 0.f;
  int d = 0;
  if (i < mc) {
    const int o = mlist[i];
    const int off = offs[o];
    d = deg[o];
    int j = 0;
    for (; j + 1 < d; j += 2) {
      int e0 = elist[off + j], e1 = elist[off + j + 1];
      u16x4_t p0 = *(const u16x4_t*)(P + (size_t)e0 * 256 + lane * 4);
      u16x4_t p1 = *(const u16x4_t*)(P + (size_t)e1 * 256 + lane * 4);
      a0 += b2f(p0.x) + b2f(p1.x);
      a1 += b2f(p0.y) + b2f(p1.y);
      a2 += b2f(p0.z) + b2f(p1.z);
      a3 += b2f(p0.w) + b2f(p1.w);
    }
    if (j < d) {
      int e0 = elist[off + j];
      u16x4_t p0 = *(const u16x4_t*)(P + (size_t)e0 * 256 + lane * 4);
      a0 += b2f(p0.x); a1 += b2f(p0.y); a2 += b2f(p0.z); a3 += b2f(p0.w);
    }
  }
  float s = 1.f / fmaxf((float)d, 1.f);
  u16x4_t pv;
  pv.x = f2b(a0 * s); pv.y = f2b(a1 * s); pv.z = f2b(a2 * s); pv.w = f2b(a3 * s);
  *(u16x4_t*)(prof + (size_t)i * 256 + lane * 4) = pv;

  u16x4_t ov;
  ov.x = f2b(xv.x); ov.y = f2b(xv.y); ov.z = f2b(xv.z); ov.w = f2b(xv.w);
  *(u16x4_t*)(objc + (size_t)i * 256 + lane * 4) = ov;
}

// ---------------- pipelined MFMA GEMM core (bf16 A, bf16 B; T3 2-phase + T2 swizzle) ----------------
// 128x128 tile, BK=64, double-buffered LDS. Per K-tile: issue next tile's
// global_load_lds BEFORE ds_read+MFMA of current, ONE barrier per tile.
// LDS XOR-swizzled both-sides (rule 21): dest linear, global SOURCE k-offset
// pre-swizzled kq=(g&7)^(row&7), ds_read applies the same involution.
template<int RELU>
__device__ __forceinline__
void gemm_core(const u16* __restrict__ A, const u16* __restrict__ B,
               const float* __restrict__ bias, u16* __restrict__ C,
               int M, int N, int n0, int m0, u16* lA, u16* lB) {
  const int tid  = threadIdx.x;
  const int lane = tid & 63;
  const int wave = tid >> 6;
  const int mR = (wave & 1) * 64;
  const int nC = (wave >> 1) * 64;

  int srow[4], skq[4];
#pragma unroll
  for (int s = 0; s < 4; ++s) {
    int g = s * 256 + tid;
    srow[s] = g >> 3;
    skq[s]  = ((g & 7) ^ ((g >> 3) & 7)) << 3;
  }

  f32x4 acc[4][4] = {};

  auto STAGE = [&](int buf, int kt) {
#pragma unroll
    for (int s = 0; s < 4; ++s) {
      int row = srow[s];
      int ar = m0 + row; ar = (ar < M) ? ar : (M - 1);
      const u16* gA = A + (size_t)ar * 256 + kt + skq[s];
      __builtin_amdgcn_global_load_lds(
          (const __attribute__((address_space(1))) void*)gA,
          (__attribute__((address_space(3))) void*)(lA + buf * 8192 + s * 2048 + wave * 512),
          16, 0, 0);
      const u16* gB = B + (size_t)(n0 + row) * 256 + kt + skq[s];
      __builtin_amdgcn_global_load_lds(
          (const __attribute__((address_space(1))) void*)gB,
          (__attribute__((address_space(3))) void*)(lB + buf * 8192 + s * 2048 + wave * 512),
          16, 0, 0);
    }
  };

  STAGE(0, 0);
  __syncthreads();

  for (int t = 0; t < 4; ++t) {
    const int cur = t & 1;
    if (t < 3) STAGE(cur ^ 1, (t + 1) * 64);
    const u16* bA = lA + cur * 8192;
    const u16* bB = lB + cur * 8192;
#pragma unroll
    for (int ks = 0; ks < 2; ++ks) {
      const int kbq = ks * 4 + (lane >> 4);
      bf16x8 af[4], bf[4];
#pragma unroll
      for (int i = 0; i < 4; ++i) {
        int ra = mR + i * 16 + (lane & 15);
        af[i] = *(const bf16x8*)(bA + ra * 64 + ((kbq ^ (ra & 7)) << 3));
        int rb = nC + i * 16 + (lane & 15);
        bf[i] = *(const bf16x8*)(bB + rb * 64 + ((kbq ^ (rb & 7)) << 3));
      }
#pragma unroll
      for (int i = 0; i < 4; ++i)
#pragma unroll
        for (int j = 0; j < 4; ++j)
          acc[i][j] = __builtin_amdgcn_mfma_f32_16x16x32_bf16(af[i], bf[j], acc[i][j], 0, 0, 0);
    }
    __syncthreads();
  }

  const int crow = (lane >> 4) * 4;
  const int ccol = lane & 15;
#pragma unroll
  for (int i = 0; i < 4; ++i) {
#pragma unroll
    for (int j = 0; j < 4; ++j) {
      int col = n0 + nC + j * 16 + ccol;
      float bv = bias[col];
#pragma unroll
      for (int q = 0; q < 4; ++q) {
        int row = m0 + mR + i * 16 + crow + q;
        if (row < M) {
          float v = acc[i][j][q] + bv;
          if (RELU) v = fmaxf(v, 0.f);
          C[(size_t)row * N + col] = f2b(v);
        }
      }
    }
  }
}

// bijective XCD swizzle (m204): consecutive wg land on one XCD's chunk
__device__ __forceinline__ int xcd_swz(int bid, int nwg) {
  int q = nwg >> 3, r = nwg & 7;
  int xcd = bid & 7, loc = bid >> 3;
  return (xcd < r ? xcd * (q + 1) : r * (q + 1) + (xcd - r) * q) + loc;
}

// ---------------- P-GEMM with fused f32->bf16 A conversion ----------------
// A is raw f32 evtX. A staged via registers (T14 split: global loads issued
// before the MFMA phase, cvt_pk+ds_write after it, one barrier per tile).
// B (weights, bf16) stays on the global_load_lds pre-swizzled path.
__global__ __launch_bounds__(256, 2)
void gemm_pf(const float* __restrict__ A, const u16* __restrict__ B,
             const float* __restrict__ bias, u16* __restrict__ C, int M, int nwg) {
  __shared__ u16 lA[2 * 8192];
  __shared__ u16 lB[2 * 8192];
  int wg = xcd_swz(blockIdx.x, nwg);
  const int n0 = (wg & 1) * 128;
  const int m0 = (wg >> 1) * 128;

  const int tid  = threadIdx.x;
  const int lane = tid & 63;
  const int wave = tid >> 6;
  const int mR = (wave & 1) * 64;
  const int nC = (wave >> 1) * 64;

  // A granule g: row=g>>3, logical q=g&7; LDS dest swizzled (q^(row&7)).
  const float* aptr[4];
  int sdst[4], skq[4], srow[4];
#pragma unroll
  for (int s = 0; s < 4; ++s) {
    int g = s * 256 + tid;
    int row = g >> 3, q = g & 7;
    srow[s] = row;
    sdst[s] = row * 64 + ((q ^ (row & 7)) << 3);
    skq[s]  = (q ^ (row & 7)) << 3;
    int ar = m0 + row; ar = (ar < M) ? ar : (M - 1);
    aptr[s] = A + (size_t)ar * 256 + q * 8;
  }

  f32x4 acc[4][4] = {};
  float4 fa[4][2];

  auto LOAD_A = [&](int kt) {
#pragma unroll
    for (int s = 0; s < 4; ++s) {
      fa[s][0] = *(const float4*)(aptr[s] + kt);
      fa[s][1] = *(const float4*)(aptr[s] + kt + 4);
    }
  };
  auto WRITE_A = [&](int buf) {
#pragma unroll
    for (int s = 0; s < 4; ++s) {
      uint4 w;
      w.x = pk2(fa[s][0].x, fa[s][0].y);
      w.y = pk2(fa[s][0].z, fa[s][0].w);
      w.z = pk2(fa[s][1].x, fa[s][1].y);
      w.w = pk2(fa[s][1].z, fa[s][1].w);
      *(uint4*)(lA + buf * 8192 + sdst[s]) = w;
    }
  };
  auto STAGE_B = [&](int buf, int kt) {
#pragma unroll
    for (int s = 0; s < 4; ++s) {
      const u16* gB = B + (size_t)(n0 + srow[s]) * 256 + kt + skq[s];
      __builtin_amdgcn_global_load_lds(
          (const __attribute__((address_space(1))) void*)gB,
          (__attribute__((address_space(3))) void*)(lB + buf * 8192 + s * 2048 + wave * 512),
          16, 0, 0);
    }
  };

  LOAD_A(0); STAGE_B(0, 0);
  WRITE_A(0);
  __syncthreads();

  for (int t = 0; t < 4; ++t) {
    const int cur = t & 1;
    if (t < 3) { LOAD_A((t + 1) * 64); STAGE_B(cur ^ 1, (t + 1) * 64); }
    const u16* bA = lA + cur * 8192;
    const u16* bB = lB + cur * 8192;
#pragma unroll
    for (int ks = 0; ks < 2; ++ks) {
      const int kbq = ks * 4 + (lane >> 4);
      bf16x8 af[4], bf[4];
#pragma unroll
      for (int i = 0; i < 4; ++i) {
        int ra = mR + i * 16 + (lane & 15);
        af[i] = *(const bf16x8*)(bA + ra * 64 + ((kbq ^ (ra & 7)) << 3));
        int rb = nC + i * 16 + (lane & 15);
        bf[i] = *(const bf16x8*)(bB + rb * 64 + ((kbq ^ (rb & 7)) << 3));
      }
#pragma unroll
      for (int i = 0; i < 4; ++i)
#pragma unroll
        for (int j = 0; j < 4; ++j)
          acc[i][j] = __builtin_amdgcn_mfma_f32_16x16x32_bf16(af[i], bf[j], acc[i][j], 0, 0, 0);
    }
    if (t < 3) WRITE_A(cur ^ 1);  // writes buf^1: fully consumed in t-1, barrier'd
    __syncthreads();
  }

  const int crow = (lane >> 4) * 4;
  const int ccol = lane & 15;
#pragma unroll
  for (int i = 0; i < 4; ++i) {
#pragma unroll
    for (int j = 0; j < 4; ++j) {
      int col = n0 + nC + j * 16 + ccol;
      float bv = bias[col];
#pragma unroll
      for (int q = 0; q < 4; ++q) {
        int row = m0 + mR + i * 16 + crow + q;
        if (row < M) {
          float v = acc[i][j][q] + bv;
          C[(size_t)row * 256 + col] = f2b(fmaxf(v, 0.f));
        }
      }
    }
  }
}

// both GRU GEMMs in one dispatch: the 12 n-tiles (6 gi + 6 gh) of one
// 128-row panel are consecutive wg -> same XCD L2 (proven: FETCH 64->20 MB)
__global__ __launch_bounds__(256, 2)
void gemm2_dual(const u16* __restrict__ prof, const u16* __restrict__ objc,
                const u16* __restrict__ wib, const u16* __restrict__ whb,
                const float* __restrict__ bi, const float* __restrict__ bh,
                u16* __restrict__ gi, u16* __restrict__ gh, int Mpad, int nwg) {
  __shared__ u16 lA[2 * 8192];
  __shared__ u16 lB[2 * 8192];
  int wg = xcd_swz(blockIdx.x, nwg);
  int m0 = (wg / 12) * 128;
  int y = wg % 12;
  if (y < 6) gemm_core<0>(prof, wib, bi, gi, Mpad, 768, y * 128, m0, lA, lB);
  else       gemm_core<0>(objc, whb, bh, gh, Mpad, 768, (y - 6) * 128, m0, lA, lB);
}

// ---------------- GRU gates + masked blend (float4-vectorized; 4 rows / block) ----------------
__global__ __launch_bounds__(256)
void gate_out(const u16* __restrict__ gi, const u16* __restrict__ gh,
              const float* __restrict__ objX, const int* __restrict__ mask,
              const int* __restrict__ cpos, float* __restrict__ out, int nObj) {
  const int wave = threadIdx.x >> 6;
  const int lane = threadIdx.x & 63;
  const int row = blockIdx.x * 4 + wave;
  if (row >= nObj) return;
  float4 x4 = *(const float4*)(objX + (size_t)row * 256 + lane * 4);
  float4 r4 = x4;
  if (mask[row]) {
    size_t b = (size_t)cpos[row] * 768 + lane * 4;
    u16x4_t ir = *(const u16x4_t*)(gi + b);
    u16x4_t iz = *(const u16x4_t*)(gi + b + 256);
    u16x4_t in_ = *(const u16x4_t*)(gi + b + 512);
    u16x4_t hr = *(const u16x4_t*)(gh + b);
    u16x4_t hz = *(const u16x4_t*)(gh + b + 256);
    u16x4_t hn = *(const u16x4_t*)(gh + b + 512);
    float xs[4] = {x4.x, x4.y, x4.z, x4.w};
    u16 irs[4] = {ir.x, ir.y, ir.z, ir.w};
    u16 izs[4] = {iz.x, iz.y, iz.z, iz.w};
    u16 ins[4] = {in_.x, in_.y, in_.z, in_.w};
    u16 hrs[4] = {hr.x, hr.y, hr.z, hr.w};
    u16 hzs[4] = {hz.x, hz.y, hz.z, hz.w};
    u16 hns[4] = {hn.x, hn.y, hn.z, hn.w};
    float rs[4];
#pragma unroll
    for (int q = 0; q < 4; ++q) {
      float r = 1.f / (1.f + __expf(-(b2f(irs[q]) + b2f(hrs[q]))));
      float z = 1.f / (1.f + __expf(-(b2f(izs[q]) + b2f(hzs[q]))));
      float a = b2f(ins[q]) + r * b2f(hns[q]);
      float n = 1.f - 2.f / (__expf(2.f * a) + 1.f);
      rs[q] = (1.f - z) * n + z * xs[q];
    }
    r4.x = rs[0]; r4.y = rs[1]; r4.z = rs[2]; r4.w = rs[3];
  }
  *(float4*)(out + (size_t)row * 256 + lane * 4) = r4;
}

// ---------------- workspace layout (bytes) ----------------
//           0  P      51,200,000  (dead after accum_gather) -> gi reuse
//  51,200,000  gh     38,535,168
//  89,735,168  prof   12,845,056
// 102,580,224  objc   12,845,056
// 115,425,280  (free; was evtb)
// 166,625,280  wb        917,504  (wpb|wib|whb)
// 167,542,784  deg       200,000  \
// 167,742,784  cursor    200,000   |  one memset zeroes
// 167,942,784  mask      200,000   |  [167,542,784 .. 168,142,912)
// 168,142,784  mcount         64   |
// 168,142,848  tcur           64  /
// 168,142,912  cpos      200,000
// 168,342,912  offs      200,000
// 168,542,912  mlist     100,352
// 168,643,264  rrows     100,352
// 168,743,616  elist   2,000,000
// total 170,743,616

extern "C" void kernel_launch(void* const* d_in, const int* in_sizes, int n_in,
                              void* d_out, int out_size, void* d_ws, size_t ws_size,
                              hipStream_t stream) {
  const float* objX   = (const float*)d_in[0];
  const float* evtX   = (const float*)d_in[1];
  const int* obj_idx  = (const int*)d_in[2];
  const int* evt_idx  = (const int*)d_in[3];
  const int* main_idx = (const int*)d_in[4];
  const float* Wp = (const float*)d_in[5];
  const float* bp = (const float*)d_in[6];
  const float* Wi = (const float*)d_in[7];
  const float* bi = (const float*)d_in[8];
  const float* Wh = (const float*)d_in[9];
  const float* bh = (const float*)d_in[10];

  const int nObj  = in_sizes[0] / 256;   // 50000
  const int nEvt  = in_sizes[1] / 256;   // 100000
  const int nEdge = in_sizes[2];         // 500000
  const int nMain = in_sizes[4];         // 25000
  const int Mpad  = ((nMain + 127) / 128) * 128;  // 25088

  char* ws = (char*)d_ws;
  u16*   P     = (u16*)(ws + 0);
  u16*   gi    = (u16*)(ws + 0);
  u16*   gh    = (u16*)(ws + 51200000);
  u16*   prof  = (u16*)(ws + 89735168);
  u16*   objc  = (u16*)(ws + 102580224);
  u16*   wb    = (u16*)(ws + 166625280);
  u16*   wpb   = wb;
  u16*   wib   = wb + 65536;
  u16*   whb   = wb + 262144;
  int*   deg   = (int*)(ws + 167542784);
  int*   cursor= (int*)(ws + 167742784);
  int*   mask  = (int*)(ws + 167942784);
  int*   mcount= (int*)(ws + 168142784);
  int*   tcur  = (int*)(ws + 168142848);
  int*   cpos  = (int*)(ws + 168142912);
  int*   offs  = (int*)(ws + 168342912);
  int*   mlist = (int*)(ws + 168542912);
  int*   rrows = (int*)(ws + 168643264);
  int*   elist = (int*)(ws + 168743616);
  float* out   = (float*)d_out;

  hipMemsetAsync(ws + 167542784, 0, 600128, stream);

  const int prepGrid = 448 + (nMain + 255) / 256;  // 546
  prep<<<prepGrid, 256, 0, stream>>>(Wp, Wi, Wh, wb,
                                     main_idx, mask, mlist, cpos, mcount, nMain);

  // P = relu(evtX @ Wp^T + bp)  [100000 x 256], f32 A converted in staging
  const int nwgP = ((nEvt + 127) / 128) * 2;  // 1564
  gemm_pf<<<nwgP, 256, 0, stream>>>(evtX, wpb, bp, P, nEvt, nwgP);

  count_edges<<<(nEdge + 255) / 256, 256, 0, stream>>>(obj_idx, mask, deg, nEdge);
  alloc_offs<<<Mpad / 256, 256, 0, stream>>>(mlist, mcount, deg, offs, tcur, rrows, Mpad);
  fill_edges<<<(nEdge + 255) / 256, 256, 0, stream>>>(obj_idx, evt_idx, mask, offs, cursor, elist, nEdge);

  accum_gather<<<(Mpad + 3) / 4, 256, 0, stream>>>(P, elist, offs, deg, mlist, mcount,
                                                   objX, rrows, prof, objc, Mpad);

  // gi = prof @ Wi^T + bi ; gh = objc @ Wh^T + bh  [25088 x 768], one dispatch
  const int nwg = (Mpad / 128) * 12;  // 2352
  gemm2_dual<<<nwg, 256, 0, stream>>>(prof, objc, wib, whb, bi, bh, gi, gh, Mpad, nwg);

  gate_out<<<(nObj + 3) / 4, 256, 0, stream>>>(gi, gh, objX, mask, cpos, out, nObj);
}

// Round 5
// 372.217 us; speedup vs baseline: 1.2066x; 1.0202x over previous
//
#include <hip/hip_runtime.h>

typedef unsigned short u16;
typedef __attribute__((ext_vector_type(8))) short bf16x8;
typedef __attribute__((ext_vector_type(4))) float f32x4;

struct __align__(8) u16x4_t { u16 x, y, z, w; };

__device__ __forceinline__ float b2f(u16 b) {
  union { unsigned u; float f; } v; v.u = ((unsigned)b) << 16; return v.f;
}
__device__ __forceinline__ u16 f2b(float f) {
  union { float f; unsigned u; } v; v.f = f;
  unsigned r = v.u + 0x7fffu + ((v.u >> 16) & 1u);
  return (u16)(r >> 16);
}
// RNE pack of two f32 into two bf16 (identical rounding to f2b)
__device__ __forceinline__ unsigned pk2(float lo, float hi) {
  unsigned r;
  asm("v_cvt_pk_bf16_f32 %0, %1, %2" : "=v"(r) : "v"(lo), "v"(hi));
  return r;
}

// ---------------- prep: weight cvt + mask/mlist build ----------------
__global__ void prep(const float* __restrict__ Wp, const float* __restrict__ Wi,
                     const float* __restrict__ Wh, u16* __restrict__ wb,
                     const int* __restrict__ main_idx, int* __restrict__ mask,
                     int* __restrict__ mlist, int* __restrict__ cpos,
                     int* __restrict__ mcount, int nMain) {
  int b = blockIdx.x;
  if (b < 448) {
    int t = b * 256 + threadIdx.x;  // [0, 114688)
    const float* src; int o;
    if (t < 16384)      { src = Wp; o = t; }
    else if (t < 65536) { src = Wi; o = t - 16384; }
    else                { src = Wh; o = t - 65536; }
    float4 v = ((const float4*)src)[o];
    u16x4_t q;
    q.x = f2b(v.x); q.y = f2b(v.y); q.z = f2b(v.z); q.w = f2b(v.w);
    ((u16x4_t*)wb)[t] = q;
  } else {
    int t = (b - 448) * 256 + threadIdx.x;
    if (t < nMain) {
      int o = main_idx[t];
      if (atomicCAS(&mask[o], 0, 1) == 0) {
        int i = atomicAdd(mcount, 1);
        mlist[i] = o;
        cpos[o] = i;
      }
    }
  }
}

// ---------------- masked degree count ----------------
__global__ void count_edges(const int* __restrict__ obj_idx, const int* __restrict__ mask,
                            int* __restrict__ deg, int n) {
  int e = blockIdx.x * 256 + threadIdx.x;
  if (e >= n) return;
  int o = obj_idx[e];
  if (mask[o]) atomicAdd(&deg[o], 1);
}

// ---------------- segment allocation ----------------
__global__ __launch_bounds__(256)
void alloc_offs(const int* __restrict__ mlist, const int* __restrict__ mcount,
                const int* __restrict__ deg, int* __restrict__ offs,
                int* __restrict__ tcur, int* __restrict__ rrows, int Mpad) {
  int i = blockIdx.x * 256 + threadIdx.x;
  int lane = threadIdx.x & 63;
  int mc = *mcount;
  if (i < Mpad) rrows[i] = (i < mc) ? mlist[i] : 0;
  int o = (i < mc) ? mlist[i] : 0;
  int d = (i < mc) ? deg[o] : 0;
  int x = d;
#pragma unroll
  for (int s = 1; s < 64; s <<= 1) {
    int y = __shfl_up(x, s, 64);
    if (lane >= s) x += y;
  }
  int wt = __shfl(x, 63, 64);
  int base = 0;
  if (lane == 63 && wt > 0) base = atomicAdd(tcur, wt);
  base = __shfl(base, 63, 64);
  if (i < mc) offs[o] = base + (x - d);
}

__global__ void fill_edges(const int* __restrict__ obj_idx, const int* __restrict__ evt_idx,
                           const int* __restrict__ mask, const int* __restrict__ offs,
                           int* __restrict__ cursor, int* __restrict__ elist, int n) {
  int e = blockIdx.x * 256 + threadIdx.x;
  if (e >= n) return;
  int o = obj_idx[e];
  if (!mask[o]) return;
  int pos = atomicAdd(&cursor[o], 1);
  elist[offs[o] + pos] = evt_idx[e];
}

// ---------------- fused: profile scatter-mean + objX gather/cvt ----------------
__global__ __launch_bounds__(256)
void accum_gather(const u16* __restrict__ P, const int* __restrict__ elist,
                  const int* __restrict__ offs, const int* __restrict__ deg,
                  const int* __restrict__ mlist, const int* __restrict__ mcount,
                  const float* __restrict__ objX, const int* __restrict__ rrows,
                  u16* __restrict__ prof, u16* __restrict__ objc, int Mpad) {
  const int wave = threadIdx.x >> 6;
  const int lane = threadIdx.x & 63;
  const int i = blockIdx.x * 4 + wave;
  if (i >= Mpad) return;

  int src = rrows[i];
  float4 xv = *(const float4*)(objX + (size_t)src * 256 + lane * 4);

  const int mc = *mcount;
  float a0 = 0.f, a1 = 0.f, a2 = 0.f, a3 = 0.f;
  int d = 0;
  if (i < mc) {
    const int o = mlist[i];
    const int off = offs[o];
    d = deg[o];
    int j = 0;
    for (; j + 1 < d; j += 2) {
      int e0 = elist[off + j], e1 = elist[off + j + 1];
      u16x4_t p0 = *(const u16x4_t*)(P + (size_t)e0 * 256 + lane * 4);
      u16x4_t p1 = *(const u16x4_t*)(P + (size_t)e1 * 256 + lane * 4);
      a0 += b2f(p0.x) + b2f(p1.x);
      a1 += b2f(p0.y) + b2f(p1.y);
      a2 += b2f(p0.z) + b2f(p1.z);
      a3 += b2f(p0.w) + b2f(p1.w);
    }
    if (j < d) {
      int e0 = elist[off + j];
      u16x4_t p0 = *(const u16x4_t*)(P + (size_t)e0 * 256 + lane * 4);
      a0 += b2f(p0.x); a1 += b2f(p0.y); a2 += b2f(p0.z); a3 += b2f(p0.w);
    }
  }
  float s = 1.f / fmaxf((float)d, 1.f);
  u16x4_t pv;
  pv.x = f2b(a0 * s); pv.y = f2b(a1 * s); pv.z = f2b(a2 * s); pv.w = f2b(a3 * s);
  *(u16x4_t*)(prof + (size_t)i * 256 + lane * 4) = pv;

  u16x4_t ov;
  ov.x = f2b(xv.x); ov.y = f2b(xv.y); ov.z = f2b(xv.z); ov.w = f2b(xv.w);
  *(u16x4_t*)(objc + (size_t)i * 256 + lane * 4) = ov;
}

// ---------------- pipelined MFMA GEMM core (bf16/bf16, R3-proven) ----------------
template<int RELU>
__device__ __forceinline__
void gemm_core(const u16* __restrict__ A, const u16* __restrict__ B,
               const float* __restrict__ bias, u16* __restrict__ C,
               int M, int N, int n0, int m0, u16* lA, u16* lB) {
  const int tid  = threadIdx.x;
  const int lane = tid & 63;
  const int wave = tid >> 6;
  const int mR = (wave & 1) * 64;
  const int nC = (wave >> 1) * 64;

  int srow[4], skq[4];
#pragma unroll
  for (int s = 0; s < 4; ++s) {
    int g = s * 256 + tid;
    srow[s] = g >> 3;
    skq[s]  = ((g & 7) ^ ((g >> 3) & 7)) << 3;
  }

  f32x4 acc[4][4] = {};

  auto STAGE = [&](int buf, int kt) {
#pragma unroll
    for (int s = 0; s < 4; ++s) {
      int row = srow[s];
      int ar = m0 + row; ar = (ar < M) ? ar : (M - 1);
      const u16* gA = A + (size_t)ar * 256 + kt + skq[s];
      __builtin_amdgcn_global_load_lds(
          (const __attribute__((address_space(1))) void*)gA,
          (__attribute__((address_space(3))) void*)(lA + buf * 8192 + s * 2048 + wave * 512),
          16, 0, 0);
      const u16* gB = B + (size_t)(n0 + row) * 256 + kt + skq[s];
      __builtin_amdgcn_global_load_lds(
          (const __attribute__((address_space(1))) void*)gB,
          (__attribute__((address_space(3))) void*)(lB + buf * 8192 + s * 2048 + wave * 512),
          16, 0, 0);
    }
  };

  STAGE(0, 0);
  __syncthreads();

  for (int t = 0; t < 4; ++t) {
    const int cur = t & 1;
    if (t < 3) STAGE(cur ^ 1, (t + 1) * 64);
    const u16* bA = lA + cur * 8192;
    const u16* bB = lB + cur * 8192;
#pragma unroll
    for (int ks = 0; ks < 2; ++ks) {
      const int kbq = ks * 4 + (lane >> 4);
      bf16x8 af[4], bf[4];
#pragma unroll
      for (int i = 0; i < 4; ++i) {
        int ra = mR + i * 16 + (lane & 15);
        af[i] = *(const bf16x8*)(bA + ra * 64 + ((kbq ^ (ra & 7)) << 3));
        int rb = nC + i * 16 + (lane & 15);
        bf[i] = *(const bf16x8*)(bB + rb * 64 + ((kbq ^ (rb & 7)) << 3));
      }
#pragma unroll
      for (int i = 0; i < 4; ++i)
#pragma unroll
        for (int j = 0; j < 4; ++j)
          acc[i][j] = __builtin_amdgcn_mfma_f32_16x16x32_bf16(af[i], bf[j], acc[i][j], 0, 0, 0);
    }
    __syncthreads();
  }

  const int crow = (lane >> 4) * 4;
  const int ccol = lane & 15;
#pragma unroll
  for (int i = 0; i < 4; ++i) {
#pragma unroll
    for (int j = 0; j < 4; ++j) {
      int col = n0 + nC + j * 16 + ccol;
      float bv = bias[col];
#pragma unroll
      for (int q = 0; q < 4; ++q) {
        int row = m0 + mR + i * 16 + crow + q;
        if (row < M) {
          float v = acc[i][j][q] + bv;
          if (RELU) v = fmaxf(v, 0.f);
          C[(size_t)row * N + col] = f2b(v);
        }
      }
    }
  }
}

// bijective XCD swizzle (m204)
__device__ __forceinline__ int xcd_swz(int bid, int nwg) {
  int q = nwg >> 3, r = nwg & 7;
  int xcd = bid & 7, loc = bid >> 3;
  return (xcd < r ? xcd * (q + 1) : r * (q + 1) + (xcd - r) * q) + loc;
}

// ---------------- P-GEMM: fused f32->bf16, f32-A-in-LDS, 128x256 tile ----------------
// A staged RAW f32 via global_load_lds (no register round-trip); conversion
// happens at the LDS->register edge (16 cvt_pk per tile, VALU prolog to MFMA).
// 512 threads, full-N tile: A panel read ONCE. BK=32 -> 8-deep pipeline.
// LDS 64KB: A f32 2x[128][32] + B bf16 2x[128][64] (paired n-rows).
// Swizzles (both-sides, rule 21):
//   A: 16B granule; row=g>>3, phys q = logical ^ (row&7). Frag read 2-way (free).
//   B: row' = n>>1 holds n-rows {2row',2row'+1}; phys q' = ((n&1)*4+h) ^ (row'&7).
//      Frag read spreads 16 lanes over 8 slots x2 (free).
__global__ __launch_bounds__(512, 2)
void gemm_pf(const float* __restrict__ A, const u16* __restrict__ B,
             const float* __restrict__ bias, u16* __restrict__ C, int M) {
  __shared__ float lA[2][128 * 32];
  __shared__ u16   lB[2][128 * 64];
  const int tid  = threadIdx.x;
  const int lane = tid & 63;
  const int wave = tid >> 6;
  const int m0 = blockIdx.x * 128;
  const int mR = (wave & 1) * 64;
  const int nC = (wave >> 1) * 64;

  // staging: 1024 granules (16B) per operand per buffer; 2 per thread each
  const float* asrc[2];
  const u16*   bsrc[2];
#pragma unroll
  for (int s = 0; s < 2; ++s) {
    int g = s * 512 + tid;
    int row = g >> 3, qp = g & 7;
    int q = qp ^ (row & 7);                 // logical k-granule for A
    int ar = m0 + row; ar = (ar < M) ? ar : (M - 1);
    asrc[s] = A + (size_t)ar * 256 + q * 4;
    int bq = qp ^ (row & 7);                // logical q' for B
    int n  = row * 2 + (bq >> 2);
    bsrc[s] = B + (size_t)n * 256 + (bq & 3) * 8;
  }

  auto STAGE = [&](int buf, int kt) {
#pragma unroll
    for (int s = 0; s < 2; ++s) {
      int g = s * 512 + tid;
      __builtin_amdgcn_global_load_lds(
          (const __attribute__((address_space(1))) void*)(asrc[s] + kt),
          (__attribute__((address_space(3))) void*)(&lA[buf][g * 4]),
          16, 0, 0);
      __builtin_amdgcn_global_load_lds(
          (const __attribute__((address_space(1))) void*)(bsrc[s] + kt),
          (__attribute__((address_space(3))) void*)(&lB[buf][g * 8]),
          16, 0, 0);
    }
  };

  f32x4 acc[4][4] = {};
  STAGE(0, 0);
  __syncthreads();

  const int h = lane >> 4;
  for (int t = 0; t < 8; ++t) {
    const int cur = t & 1;
    if (t < 7) STAGE(cur ^ 1, (t + 1) * 32);
    const float* bA = lA[cur];
    const u16*   bB = lB[cur];
    bf16x8 af[4], bf[4];
#pragma unroll
    for (int i = 0; i < 4; ++i) {
      int ra = mR + i * 16 + (lane & 15);
      int pg = (2 * h) ^ (ra & 7);
      // content at phys p is logical p^(ra&7): pg -> 2h (k=8h..8h+3), pg^1 -> 2h+1
      float4 x = *(const float4*)(bA + ra * 32 + pg * 4);
      float4 y = *(const float4*)(bA + ra * 32 + (pg ^ 1) * 4);
      union { unsigned u[4]; bf16x8 v; } cv;
      cv.u[0] = pk2(x.x, x.y); cv.u[1] = pk2(x.z, x.w);
      cv.u[2] = pk2(y.x, y.y); cv.u[3] = pk2(y.z, y.w);
      af[i] = cv.v;
    }
#pragma unroll
    for (int j = 0; j < 4; ++j) {
      int rb = nC + j * 16 + (lane & 15);
      int qp = (((rb & 1) << 2) | h) ^ ((rb >> 1) & 7);
      bf[j] = *(const bf16x8*)(bB + (rb >> 1) * 64 + qp * 8);
    }
#pragma unroll
    for (int i = 0; i < 4; ++i)
#pragma unroll
      for (int j = 0; j < 4; ++j)
        acc[i][j] = __builtin_amdgcn_mfma_f32_16x16x32_bf16(af[i], bf[j], acc[i][j], 0, 0, 0);
    __syncthreads();
  }

  const int crow = (lane >> 4) * 4;
  const int ccol = lane & 15;
#pragma unroll
  for (int i = 0; i < 4; ++i) {
#pragma unroll
    for (int j = 0; j < 4; ++j) {
      int col = nC + j * 16 + ccol;
      float bv = bias[col];
#pragma unroll
      for (int q = 0; q < 4; ++q) {
        int row = m0 + mR + i * 16 + crow + q;
        if (row < M)
          C[(size_t)row * 256 + col] = f2b(fmaxf(acc[i][j][q] + bv, 0.f));
      }
    }
  }
}

// both GRU GEMMs in one dispatch; XCD swizzle proven (FETCH 64->20 MB)
__global__ __launch_bounds__(256, 2)
void gemm2_dual(const u16* __restrict__ prof, const u16* __restrict__ objc,
                const u16* __restrict__ wib, const u16* __restrict__ whb,
                const float* __restrict__ bi, const float* __restrict__ bh,
                u16* __restrict__ gi, u16* __restrict__ gh, int Mpad, int nwg) {
  __shared__ u16 lA[2 * 8192];
  __shared__ u16 lB[2 * 8192];
  int wg = xcd_swz(blockIdx.x, nwg);
  int m0 = (wg / 12) * 128;
  int y = wg % 12;
  if (y < 6) gemm_core<0>(prof, wib, bi, gi, Mpad, 768, y * 128, m0, lA, lB);
  else       gemm_core<0>(objc, whb, bh, gh, Mpad, 768, (y - 6) * 128, m0, lA, lB);
}

// ---------------- GRU gates + masked blend ----------------
__global__ __launch_bounds__(256)
void gate_out(const u16* __restrict__ gi, const u16* __restrict__ gh,
              const float* __restrict__ objX, const int* __restrict__ mask,
              const int* __restrict__ cpos, float* __restrict__ out, int nObj) {
  const int wave = threadIdx.x >> 6;
  const int lane = threadIdx.x & 63;
  const int row = blockIdx.x * 4 + wave;
  if (row >= nObj) return;
  float4 x4 = *(const float4*)(objX + (size_t)row * 256 + lane * 4);
  float4 r4 = x4;
  if (mask[row]) {
    size_t b = (size_t)cpos[row] * 768 + lane * 4;
    u16x4_t ir = *(const u16x4_t*)(gi + b);
    u16x4_t iz = *(const u16x4_t*)(gi + b + 256);
    u16x4_t in_ = *(const u16x4_t*)(gi + b + 512);
    u16x4_t hr = *(const u16x4_t*)(gh + b);
    u16x4_t hz = *(const u16x4_t*)(gh + b + 256);
    u16x4_t hn = *(const u16x4_t*)(gh + b + 512);
    float xs[4] = {x4.x, x4.y, x4.z, x4.w};
    u16 irs[4] = {ir.x, ir.y, ir.z, ir.w};
    u16 izs[4] = {iz.x, iz.y, iz.z, iz.w};
    u16 ins[4] = {in_.x, in_.y, in_.z, in_.w};
    u16 hrs[4] = {hr.x, hr.y, hr.z, hr.w};
    u16 hzs[4] = {hz.x, hz.y, hz.z, hz.w};
    u16 hns[4] = {hn.x, hn.y, hn.z, hn.w};
    float rs[4];
#pragma unroll
    for (int q = 0; q < 4; ++q) {
      float r = 1.f / (1.f + __expf(-(b2f(irs[q]) + b2f(hrs[q]))));
      float z = 1.f / (1.f + __expf(-(b2f(izs[q]) + b2f(hzs[q]))));
      float a = b2f(ins[q]) + r * b2f(hns[q]);
      float n = 1.f - 2.f / (__expf(2.f * a) + 1.f);
      rs[q] = (1.f - z) * n + z * xs[q];
    }
    r4.x = rs[0]; r4.y = rs[1]; r4.z = rs[2]; r4.w = rs[3];
  }
  *(float4*)(out + (size_t)row * 256 + lane * 4) = r4;
}

// ---------------- workspace layout (bytes) ----------------
//           0  P      51,200,000  (dead after accum_gather) -> gi reuse
//  51,200,000  gh     38,535,168
//  89,735,168  prof   12,845,056
// 102,580,224  objc   12,845,056
// 166,625,280  wb        917,504  (wpb|wib|whb)
// 167,542,784  deg       200,000  \
// 167,742,784  cursor    200,000   |  one memset zeroes
// 167,942,784  mask      200,000   |  [167,542,784 .. 168,142,912)
// 168,142,784  mcount         64   |
// 168,142,848  tcur           64  /
// 168,142,912  cpos      200,000
// 168,342,912  offs      200,000
// 168,542,912  mlist     100,352
// 168,643,264  rrows     100,352
// 168,743,616  elist   2,000,000

extern "C" void kernel_launch(void* const* d_in, const int* in_sizes, int n_in,
                              void* d_out, int out_size, void* d_ws, size_t ws_size,
                              hipStream_t stream) {
  const float* objX   = (const float*)d_in[0];
  const float* evtX   = (const float*)d_in[1];
  const int* obj_idx  = (const int*)d_in[2];
  const int* evt_idx  = (const int*)d_in[3];
  const int* main_idx = (const int*)d_in[4];
  const float* Wp = (const float*)d_in[5];
  const float* bp = (const float*)d_in[6];
  const float* Wi = (const float*)d_in[7];
  const float* bi = (const float*)d_in[8];
  const float* Wh = (const float*)d_in[9];
  const float* bh = (const float*)d_in[10];

  const int nObj  = in_sizes[0] / 256;   // 50000
  const int nEvt  = in_sizes[1] / 256;   // 100000
  const int nEdge = in_sizes[2];         // 500000
  const int nMain = in_sizes[4];         // 25000
  const int Mpad  = ((nMain + 127) / 128) * 128;  // 25088

  char* ws = (char*)d_ws;
  u16*   P     = (u16*)(ws + 0);
  u16*   gi    = (u16*)(ws + 0);
  u16*   gh    = (u16*)(ws + 51200000);
  u16*   prof  = (u16*)(ws + 89735168);
  u16*   objc  = (u16*)(ws + 102580224);
  u16*   wb    = (u16*)(ws + 166625280);
  u16*   wpb   = wb;
  u16*   wib   = wb + 65536;
  u16*   whb   = wb + 262144;
  int*   deg   = (int*)(ws + 167542784);
  int*   cursor= (int*)(ws + 167742784);
  int*   mask  = (int*)(ws + 167942784);
  int*   mcount= (int*)(ws + 168142784);
  int*   tcur  = (int*)(ws + 168142848);
  int*   cpos  = (int*)(ws + 168142912);
  int*   offs  = (int*)(ws + 168342912);
  int*   mlist = (int*)(ws + 168542912);
  int*   rrows = (int*)(ws + 168643264);
  int*   elist = (int*)(ws + 168743616);
  float* out   = (float*)d_out;

  hipMemsetAsync(ws + 167542784, 0, 600128, stream);

  const int prepGrid = 448 + (nMain + 255) / 256;  // 546
  prep<<<prepGrid, 256, 0, stream>>>(Wp, Wi, Wh, wb,
                                     main_idx, mask, mlist, cpos, mcount, nMain);

  // P = relu(evtX @ Wp^T + bp)  [100000 x 256]; f32 A staged raw, cvt at LDS edge
  gemm_pf<<<(nEvt + 127) / 128, 512, 0, stream>>>(evtX, wpb, bp, P, nEvt);

  count_edges<<<(nEdge + 255) / 256, 256, 0, stream>>>(obj_idx, mask, deg, nEdge);
  alloc_offs<<<Mpad / 256, 256, 0, stream>>>(mlist, mcount, deg, offs, tcur, rrows, Mpad);
  fill_edges<<<(nEdge + 255) / 256, 256, 0, stream>>>(obj_idx, evt_idx, mask, offs, cursor, elist, nEdge);

  accum_gather<<<(Mpad + 3) / 4, 256, 0, stream>>>(P, elist, offs, deg, mlist, mcount,
                                                   objX, rrows, prof, objc, Mpad);

  const int nwg = (Mpad / 128) * 12;  // 2352
  gemm2_dual<<<nwg, 256, 0, stream>>>(prof, objc, wib, whb, bi, bh, gi, gh, Mpad, nwg);

  gate_out<<<(nObj + 3) / 4, 256, 0, stream>>>(gi, gh, objX, mask, cpos, out, nObj);
}